// Round 1
// baseline (320.321 us; speedup 1.0000x reference)
//
#include <hip/hip_runtime.h>
#include <math.h>

#define VOCAB 1024
#define ED 64
#define NROWS 65536            // 64*32*32 flattened rows
#define NELEM 4194304          // 64*64*32*32
#define MARGIN 2.0e-4f         // validated R3/R4 (passed, absmax 0)
#define CAPF 8192              // flagged-row slots (expect ~2500-4200)

typedef __attribute__((ext_vector_type(8))) short short8;
typedef __attribute__((ext_vector_type(4))) float f32x4;

__device__ __forceinline__ unsigned f2bf(float f) {
    unsigned u = __float_as_uint(f);
    u += 0x7fff + ((u >> 16) & 1);   // RNE to bf16
    return u >> 16;
}

// ws layout:
//   [0,     4096)   float e2f[1024]     fl32(fp64 ||e||^2)  (R2-proven)
//   [4096,  4104)   double loss_sum
//   [4104,  4108)   unsigned nflag
//   [4108,  4112)   pad
//   [4112,  8208)   unsigned hist[1024]
//   [8208,  40976)  unsigned rowlist[CAPF]
//   [40976, 172048) uint4 FB[8192]      bf16 MFMA-B fragments (128 KB)
//
// FB fragment layout (identical bits to the old per-block stage_chunk):
//   entry i: n=i&15, q=(i>>4)&3, kh=(i>>6)&1, T=i>>7
//   holds bf16x8 of emb[T*16+n][kh*32+q*8 .. +8)
//   filter reads bf[kh] = ((short8*)FB)[T*128 + kh*64 + lane], lane=q*16+n_lo

// ---------------- prep: e2f + bf16 fragment table ----------------
__global__ void vq_prep(const float* __restrict__ emb, float* __restrict__ e2f,
                        uint4* __restrict__ FB) {
    const int tid = blockIdx.x * 256 + threadIdx.x;   // 0..2047
    if (tid < VOCAB) {
        const float4* src = (const float4*)(emb + tid * ED);
        double s = 0.0;
        #pragma unroll
        for (int g = 0; g < 16; ++g) {
            float4 f = src[g];
            s = fma((double)f.x, (double)f.x, s);
            s = fma((double)f.y, (double)f.y, s);
            s = fma((double)f.z, (double)f.z, s);
            s = fma((double)f.w, (double)f.w, s);
        }
        e2f[tid] = (float)s;
    }
    #pragma unroll
    for (int e = 0; e < 4; ++e) {
        const int i = e * 2048 + tid;                 // 0..8191
        const int n = i & 15, q = (i >> 4) & 3, kh = (i >> 6) & 1, T = i >> 7;
        const int code = T * 16 + n;
        const int k0 = kh * 32 + q * 8;
        const float4* sp = (const float4*)(emb + code * 64 + k0);
        float4 f0 = sp[0], f1 = sp[1];
        uint4 pk;
        pk.x = f2bf(f0.x) | (f2bf(f0.y) << 16);
        pk.y = f2bf(f0.z) | (f2bf(f0.w) << 16);
        pk.z = f2bf(f1.x) | (f2bf(f1.y) << 16);
        pk.w = f2bf(f1.z) | (f2bf(f1.w) << 16);
        FB[i] = pk;
    }
}

// ---------------- filter: single MFMA scan, top-2, flag, epilogue ----------------
__global__ __launch_bounds__(256, 1)
void vq_filter(const float* __restrict__ z, const float* __restrict__ emb,
               const float* __restrict__ e2f, const uint4* __restrict__ FB,
               float* __restrict__ out, double* __restrict__ loss_sum,
               unsigned* __restrict__ hist, unsigned* __restrict__ nflag,
               unsigned* __restrict__ rowlist) {
    __shared__ float e2s[1024];
    __shared__ float rowb1[256], rowb2[256];
    __shared__ int   rowi1[256];

    const int t = threadIdx.x;
    const int w = t >> 6, lane = t & 63;
    const int q = lane >> 4, n_lo = lane & 15;
    const int bk = blockIdx.x;        // 256 blocks, 256 rows each
    const int n0 = bk * 256;
    const int b  = n0 >> 10;
    const int sb = n0 & 1023;

    #pragma unroll
    for (int i = 0; i < 4; ++i) e2s[i * 256 + t] = e2f[i * 256 + t];

    // A fragments: bf16(-2 z) for this wave's 64 rows (bit-identical to prior kernel)
    short8 af[4][2];
    #pragma unroll
    for (int rt = 0; rt < 4; ++rt) {
        const int s = sb + w * 64 + rt * 16 + n_lo;
        const float* zp = z + (size_t)b * 65536 + s;
        #pragma unroll
        for (int kh = 0; kh < 2; ++kh) {
            short8 fr;
            #pragma unroll
            for (int j = 0; j < 8; ++j) {
                int d = kh * 32 + q * 8 + j;
                fr[j] = (short)f2bf(-2.0f * zp[d * 1024]);
            }
            af[rt][kh] = fr;
        }
    }

    float b1[16], b2[16]; int i1[16];
    #pragma unroll
    for (int sl = 0; sl < 16; ++sl) { b1[sl] = 3.4e38f; b2[sl] = 3.4e38f; i1[sl] = 0; }

    __syncthreads();                  // e2s ready

    // ---- MFMA scan over all 64 16-code tiles, B-fragments straight from global ----
    const short8* FBs = (const short8*)FB;
    #pragma unroll 2
    for (int T = 0; T < 64; ++T) {
        short8 bf0 = FBs[T * 128 + lane];          // kh=0
        short8 bf1 = FBs[T * 128 + 64 + lane];     // kh=1
        const int cb = T * 16 + n_lo;
        const float e2 = e2s[cb];
        #pragma unroll
        for (int rt = 0; rt < 4; ++rt) {
            f32x4 a; a[0] = e2; a[1] = e2; a[2] = e2; a[3] = e2;
            a = __builtin_amdgcn_mfma_f32_16x16x32_bf16(af[rt][0], bf0, a, 0, 0, 0);
            a = __builtin_amdgcn_mfma_f32_16x16x32_bf16(af[rt][1], bf1, a, 0, 0, 0);
            #pragma unroll
            for (int reg = 0; reg < 4; ++reg) {
                const int sl = rt * 4 + reg;
                float s0 = a[reg];
                b2[sl] = __builtin_amdgcn_fmed3f(s0, b1[sl], b2[sl]);
                bool lt0 = s0 < b1[sl];
                i1[sl] = lt0 ? cb : i1[sl];
                b1[sl] = lt0 ? s0 : b1[sl];
            }
        }
    }

    // merge across the 16 code-lanes of each quad (unchanged)
    #pragma unroll
    for (int m = 1; m < 16; m <<= 1) {
        #pragma unroll
        for (int sl = 0; sl < 16; ++sl) {
            float ob1 = __shfl_xor(b1[sl], m, 64);
            int   oi1 = __shfl_xor(i1[sl], m, 64);
            float ob2 = __shfl_xor(b2[sl], m, 64);
            float lose = fmaxf(b1[sl], ob1);
            b2[sl] = fminf(fminf(b2[sl], ob2), lose);
            bool take = (ob1 < b1[sl]) || (ob1 == b1[sl] && oi1 < i1[sl]);
            b1[sl] = take ? ob1 : b1[sl];
            i1[sl] = take ? oi1 : i1[sl];
        }
    }
    if (n_lo == 0) {
        #pragma unroll
        for (int rt = 0; rt < 4; ++rt) {
            #pragma unroll
            for (int reg = 0; reg < 4; ++reg) {
                int row = w * 64 + rt * 16 + q * 4 + reg;
                int sl = rt * 4 + reg;
                rowb1[row] = b1[sl];
                rowb2[row] = b2[sl];
                rowi1[row] = i1[sl];
            }
        }
    }
    __syncthreads();

    // ---- flag rows; index + hist for unflagged (thread t owns row t) ----
    const int nrow = n0 + t;
    const int code = rowi1[t];
    bool fl = false;
    if (rowb2[t] < rowb1[t] + MARGIN) {
        unsigned p = atomicAdd(nflag, 1u);
        if (p < CAPF) { rowlist[p] = (unsigned)nrow; fl = true; }
        // overflow (p>=CAPF): treated as unflagged, same as prior kernel
    }
    out[NELEM + nrow] = (float)code;   // rescue overwrites if flagged
    if (!fl) atomicAdd(&hist[code], 1u);

    // ---- epilogue: COALESCED z_q_st + loss. Thread t owns row t. ----
    {
        const int scol = sb + t;
        double lsum = 0.0;
        #pragma unroll
        for (int d4 = 0; d4 < 16; ++d4) {
            float4 e4 = *(const float4*)(emb + code * 64 + d4 * 4);  // gather, L1/L2-hot
            float es[4] = {e4.x, e4.y, e4.z, e4.w};
            #pragma unroll
            for (int j = 0; j < 4; ++j) {
                int d = d4 * 4 + j;
                size_t off = (size_t)b * 65536 + (size_t)d * 1024 + scol;
                float zv = z[off];                 // coalesced 1 KB/wave
                out[off] = zv + (es[j] - zv);      // coalesced 1 KB/wave
                double df = (double)es[j] - (double)zv;
                lsum = fma(df, df, lsum);
            }
        }
        if (fl) lsum = 0.0;                        // rescue adds flagged rows' loss
        #pragma unroll
        for (int off = 32; off > 0; off >>= 1)
            lsum += __shfl_down(lsum, off, 64);
        if (lane == 0) atomicAdd(loss_sum, lsum);
    }
}

// ---------------- rescue: one WAVE per flagged row, exact R2 chain over ALL codes ----------------
__global__ __launch_bounds__(256, 1)
void vq_rescue(const float* __restrict__ z, const float* __restrict__ emb,
               const float* __restrict__ e2f, float* __restrict__ out,
               double* __restrict__ loss_sum, unsigned* __restrict__ hist,
               const unsigned* __restrict__ nflag,
               const unsigned* __restrict__ rowlist) {
    const int w = threadIdx.x >> 6, lane = threadIdx.x & 63;
    unsigned nfr = *nflag;
    const int nf = (int)(nfr < CAPF ? nfr : CAPF);
    const int slot = blockIdx.x * 4 + w;
    if (slot >= nf) return;
    const int row = (int)rowlist[slot];
    const int b = row >> 10, s = row & 1023;

    // every lane holds the full z row (broadcast loads, L2/L3-hot)
    float zr[64];
    #pragma unroll
    for (int k = 0; k < 64; ++k)
        zr[k] = z[(size_t)b * 65536 + (size_t)k * 1024 + s];

    double a = 0.0;
    #pragma unroll
    for (int k = 0; k < 64; ++k) a = fma((double)zr[k], (double)zr[k], a);
    const float zn = (float)a;        // fl32(fp64 ||z||^2), R2-proven

    // lane handles codes cc*64+lane (ascending per lane); exact sequential-k fp32 chain
    float bv = 3.4e38f; int bi = 0x7fffffff;
    #pragma unroll 4
    for (int cc = 0; cc < 16; ++cc) {
        const int c = cc * 64 + lane;
        float m = 0.f;
        const float4* ep = (const float4*)(emb + c * 64);
        #pragma unroll
        for (int k4 = 0; k4 < 16; ++k4) {            // strict sequential k (R2-exact)
            float4 e4 = ep[k4];
            m = fmaf(zr[4*k4+0], e4.x, m); m = fmaf(zr[4*k4+1], e4.y, m);
            m = fmaf(zr[4*k4+2], e4.z, m); m = fmaf(zr[4*k4+3], e4.w, m);
        }
        float tt = zn + e2f[c];
        float d = tt - 2.0f * m;
        if (d < bv || (d == bv && c < bi)) { bv = d; bi = c; }
    }
    // wave-wide lexicographic (value, index) min — first-occurrence semantics
    #pragma unroll
    for (int mo = 32; mo > 0; mo >>= 1) {
        float ob = __shfl_xor(bv, mo, 64);
        int   oi = __shfl_xor(bi, mo, 64);
        if (ob < bv || (ob == bv && oi < bi)) { bv = ob; bi = oi; }
    }

    // outputs: lane k handles dim k (coalesced emb read; strided 4B out writes, ~1 MB total)
    const float e = emb[bi * 64 + lane];
    const size_t off = (size_t)b * 65536 + (size_t)lane * 1024 + s;
    const float zv = z[off];                        // reload (L2-hot) — avoids zr[lane] scratch
    out[off] = zv + (e - zv);
    double df = (double)e - (double)zv;
    double lsum = df * df;
    #pragma unroll
    for (int o = 32; o > 0; o >>= 1) lsum += __shfl_down(lsum, o, 64);
    if (lane == 0) {
        out[NELEM + row] = (float)bi;
        atomicAdd(&hist[bi], 1u);
        atomicAdd(loss_sum, lsum);
    }
}

// ---------------- finalize ----------------
__global__ void vq_finalize_kernel(const unsigned* __restrict__ hist,
                                   const double* __restrict__ loss_sum,
                                   float* __restrict__ out) {
    __shared__ double red[256];
    int t = threadIdx.x;
    double ssum = 0.0;
    for (int i = t; i < VOCAB; i += 256) {
        double p = (double)hist[i] / (double)NROWS;
        ssum += p * log(p + 1e-10);
    }
    red[t] = ssum;
    __syncthreads();
    for (int off = 128; off > 0; off >>= 1) {
        if (t < off) red[t] += red[t + off];
        __syncthreads();
    }
    if (t == 0) {
        double qv = loss_sum[0] / (double)NELEM;
        out[NELEM + NROWS + 0] = (float)qv;
        out[NELEM + NROWS + 1] = (float)(qv * 0.25);
        out[NELEM + NROWS + 2] = (float)exp(-red[0]);
    }
}

extern "C" void kernel_launch(void* const* d_in, const int* in_sizes, int n_in,
                              void* d_out, int out_size, void* d_ws, size_t ws_size,
                              hipStream_t stream) {
    const float* z   = (const float*)d_in[0];   // (64,64,32,32) fp32
    const float* emb = (const float*)d_in[1];   // (1024,64) fp32
    float* out = (float*)d_out;

    float*    e2f     = (float*)d_ws;
    double*   loss    = (double*)((char*)d_ws + 4096);
    unsigned* nfl     = (unsigned*)((char*)d_ws + 4104);
    unsigned* hist    = (unsigned*)((char*)d_ws + 4112);
    unsigned* rowlist = (unsigned*)((char*)d_ws + 8208);
    uint4*    FB      = (uint4*)((char*)d_ws + 40976);

    // zero loss + nflag + pad + hist
    hipMemsetAsync((char*)d_ws + 4096, 0, 4112, stream);

    vq_prep<<<dim3(8), dim3(256), 0, stream>>>(emb, e2f, FB);
    vq_filter<<<dim3(256), dim3(256), 0, stream>>>(z, emb, e2f, FB, out, loss,
                                                   hist, nfl, rowlist);
    vq_rescue<<<dim3(CAPF / 4), dim3(256), 0, stream>>>(z, emb, e2f, out, loss,
                                                        hist, nfl, rowlist);
    vq_finalize_kernel<<<dim3(1), dim3(256), 0, stream>>>(hist, loss, out);
}

// Round 2
// 299.402 us; speedup vs baseline: 1.0699x; 1.0699x over previous
//
#include <hip/hip_runtime.h>
#include <math.h>

#define VOCAB 1024
#define ED 64
#define NROWS 65536            // 64*32*32 flattened rows
#define NELEM 4194304          // 64*64*32*32
#define MARGIN 2.0e-4f         // validated R3/R4 (passed, absmax 0)
#define CAPF 8192              // flagged-row slots (expect ~2500-4200)

typedef __attribute__((ext_vector_type(8))) short short8;
typedef __attribute__((ext_vector_type(4))) float f32x4;

__device__ __forceinline__ unsigned f2bf(float f) {
    unsigned u = __float_as_uint(f);
    u += 0x7fff + ((u >> 16) & 1);   // RNE to bf16
    return u >> 16;
}

// pack (distance, code) into a sortable u64 key: min(key) == lex-min (d, c)
__device__ __forceinline__ unsigned long long packkey(float d, int c) {
    unsigned f = __float_as_uint(d);
    unsigned sd = (f & 0x80000000u) ? ~f : (f | 0x80000000u);
    return ((unsigned long long)sd << 32) | (unsigned)c;
}

// ws layout:
//   [0,      4096)   float e2f[1024]     fl32(fp64 ||e||^2)  (R2-proven)
//   [4096,   4104)   double loss_sum
//   [4104,   4108)   unsigned nflag
//   [4108,   4112)   pad
//   [4112,   8208)   unsigned hist[1024]
//   [8208,   40976)  unsigned rowlist[CAPF]
//   [40976,  172048) uint4 FB[8192]      bf16 MFMA-B fragments (128 KB)
//   [172048, 237584) u64 keyws[CAPF]     rescue (dist,code) keys, init 0xFF
//
// FB fragment layout (identical bits to round-0 stage_chunk):
//   entry i: n=i&15, q=(i>>4)&3, kh=(i>>6)&1, T=i>>7
//   holds bf16x8 of emb[T*16+n][kh*32+q*8 .. +8)
//   filter reads bf[kh] = ((short8*)FBchunk)[tt*128 + kh*64 + lane], lane=q*16+n_lo

// ---------------- prep: e2f + bf16 fragment table ----------------
__global__ void vq_prep(const float* __restrict__ emb, float* __restrict__ e2f,
                        uint4* __restrict__ FB) {
    const int tid = blockIdx.x * 256 + threadIdx.x;   // 0..2047
    if (tid < VOCAB) {
        const float4* src = (const float4*)(emb + tid * ED);
        double s = 0.0;
        #pragma unroll
        for (int g = 0; g < 16; ++g) {
            float4 f = src[g];
            s = fma((double)f.x, (double)f.x, s);
            s = fma((double)f.y, (double)f.y, s);
            s = fma((double)f.z, (double)f.z, s);
            s = fma((double)f.w, (double)f.w, s);
        }
        e2f[tid] = (float)s;
    }
    #pragma unroll
    for (int e = 0; e < 4; ++e) {
        const int i = e * 2048 + tid;                 // 0..8191
        const int n = i & 15, q = (i >> 4) & 3, kh = (i >> 6) & 1, T = i >> 7;
        const int code = T * 16 + n;
        const int k0 = kh * 32 + q * 8;
        const float4* sp = (const float4*)(emb + code * 64 + k0);
        float4 f0 = sp[0], f1 = sp[1];
        uint4 pk;
        pk.x = f2bf(f0.x) | (f2bf(f0.y) << 16);
        pk.y = f2bf(f0.z) | (f2bf(f0.w) << 16);
        pk.z = f2bf(f1.x) | (f2bf(f1.y) << 16);
        pk.w = f2bf(f1.z) | (f2bf(f1.w) << 16);
        FB[i] = pk;
    }
}

// ---------------- filter: 1024 blocks x 64 rows, 16 rows/wave, LDS-staged FB ----------------
__global__ __launch_bounds__(256, 4)
void vq_filter(const float* __restrict__ z, const float* __restrict__ emb,
               const float* __restrict__ e2f, const uint4* __restrict__ FB,
               float* __restrict__ out, double* __restrict__ loss_sum,
               unsigned* __restrict__ hist, unsigned* __restrict__ nflag,
               unsigned* __restrict__ rowlist) {
    __shared__ uint4 Bs4[2048];          // 32 KB: one 16-tile FB chunk
    __shared__ float e2s[1024];
    __shared__ float rowb1[64], rowb2[64];
    __shared__ int   rowi1[64], rowfl[64];

    const int t = threadIdx.x;
    const int w = t >> 6, lane = t & 63;
    const int q = lane >> 4, n_lo = lane & 15;
    const int bk = blockIdx.x;           // 1024 blocks, 64 rows each
    const int n0 = bk * 64;
    const int b  = n0 >> 10;
    const int sb = n0 & 1023;

    #pragma unroll
    for (int i = 0; i < 4; ++i) e2s[i * 256 + t] = e2f[i * 256 + t];

    // A fragments: bf16(-2 z) for this wave's 16 rows (bit-identical values per row)
    short8 af[2];
    {
        const int s = sb + w * 16 + n_lo;
        const float* zp = z + (size_t)b * 65536 + s;
        #pragma unroll
        for (int kh = 0; kh < 2; ++kh) {
            short8 fr;
            #pragma unroll
            for (int j = 0; j < 8; ++j) {
                int d = kh * 32 + q * 8 + j;
                fr[j] = (short)f2bf(-2.0f * zp[d * 1024]);
            }
            af[kh] = fr;
        }
    }

    float b1[4], b2[4]; int i1[4];
    #pragma unroll
    for (int sl = 0; sl < 4; ++sl) { b1[sl] = 3.4e38f; b2[sl] = 3.4e38f; i1[sl] = 0; }

    // ---- MFMA scan: 4 chunks x 16 tiles, FB staged through LDS ----
    for (int cc = 0; cc < 4; ++cc) {
        __syncthreads();                 // Bs free (and e2s ready on cc=0)
        {
            const uint4* src = FB + cc * 2048;
            #pragma unroll
            for (int i = 0; i < 8; ++i) Bs4[i * 256 + t] = src[i * 256 + t];
        }
        __syncthreads();                 // chunk staged
        #pragma unroll 4
        for (int tt = 0; tt < 16; ++tt) {
            short8 bf0 = ((const short8*)Bs4)[tt * 128 + lane];        // kh=0
            short8 bf1 = ((const short8*)Bs4)[tt * 128 + 64 + lane];   // kh=1
            const int cb = (cc * 16 + tt) * 16 + n_lo;
            const float e2 = e2s[cb];
            f32x4 a; a[0] = e2; a[1] = e2; a[2] = e2; a[3] = e2;
            a = __builtin_amdgcn_mfma_f32_16x16x32_bf16(af[0], bf0, a, 0, 0, 0);
            a = __builtin_amdgcn_mfma_f32_16x16x32_bf16(af[1], bf1, a, 0, 0, 0);
            #pragma unroll
            for (int reg = 0; reg < 4; ++reg) {
                float s0 = a[reg];
                b2[reg] = __builtin_amdgcn_fmed3f(s0, b1[reg], b2[reg]);
                bool lt = s0 < b1[reg];
                i1[reg] = lt ? cb : i1[reg];
                b1[reg] = lt ? s0 : b1[reg];
            }
        }
    }

    // merge across the 16 code-lanes of each quad (identical to validated logic)
    #pragma unroll
    for (int m = 1; m < 16; m <<= 1) {
        #pragma unroll
        for (int sl = 0; sl < 4; ++sl) {
            float ob1 = __shfl_xor(b1[sl], m, 64);
            int   oi1 = __shfl_xor(i1[sl], m, 64);
            float ob2 = __shfl_xor(b2[sl], m, 64);
            float lose = fmaxf(b1[sl], ob1);
            b2[sl] = fminf(fminf(b2[sl], ob2), lose);
            bool take = (ob1 < b1[sl]) || (ob1 == b1[sl] && oi1 < i1[sl]);
            b1[sl] = take ? ob1 : b1[sl];
            i1[sl] = take ? oi1 : i1[sl];
        }
    }
    if (n_lo == 0) {
        #pragma unroll
        for (int reg = 0; reg < 4; ++reg) {
            int row = w * 16 + q * 4 + reg;
            rowb1[row] = b1[reg];
            rowb2[row] = b2[reg];
            rowi1[row] = i1[reg];
        }
    }
    __syncthreads();

    // ---- flag rows; index + hist for unflagged ----
    if (t < 64) {
        const int nrow = n0 + t;
        const int code = rowi1[t];
        int f = 0;
        if (rowb2[t] < rowb1[t] + MARGIN) {
            unsigned p = atomicAdd(nflag, 1u);
            if (p < CAPF) { rowlist[p] = (unsigned)nrow; f = 1; }
            // overflow (p>=CAPF): treated unflagged, same as validated kernel
        }
        rowfl[t] = f;
        out[NELEM + nrow] = (float)code;   // rescue overwrites if flagged
        if (!f) atomicAdd(&hist[code], 1u);
    }
    __syncthreads();

    // ---- epilogue: COALESCED z_q_st + loss. Thread (w,lane): row=lane, dims [w*16,w*16+16) ----
    {
        const int r = lane;
        const int code2 = rowi1[r];
        const bool fl2 = rowfl[r] != 0;
        const int scol = sb + r;
        double lsum = 0.0;
        #pragma unroll
        for (int i = 0; i < 4; ++i) {
            const int d4 = w * 4 + i;
            float4 e4 = *(const float4*)(emb + code2 * 64 + d4 * 4);  // gather, L1/L2-hot
            float es[4] = {e4.x, e4.y, e4.z, e4.w};
            #pragma unroll
            for (int j = 0; j < 4; ++j) {
                int d = d4 * 4 + j;
                size_t off = (size_t)b * 65536 + (size_t)d * 1024 + scol;
                float zv = z[off];                 // coalesced 256B
                out[off] = zv + (es[j] - zv);      // coalesced 256B
                double df = (double)es[j] - (double)zv;
                lsum = fma(df, df, lsum);
            }
        }
        if (fl2) lsum = 0.0;                       // rescue adds flagged rows' loss
        #pragma unroll
        for (int off = 32; off > 0; off >>= 1)
            lsum += __shfl_down(lsum, off, 64);
        if (lane == 0) atomicAdd(loss_sum, lsum);
    }
}

// ---------------- rescue scan: lane<->row, broadcast codes, atomicMin key merge ----------------
// grid = (CAPF/64) * 4 blocks of 256: block = (rowgroup g, chunk-quad cg); wave w scans
// codes [ (cg*4+w)*64, +64 ) for the 64 rows of group g. Exact R2 fp32 chain per code.
#define ZLD(i)  float4 zz##i = zrp[i];
#define ZN4(i)  a = fma((double)zz##i.x,(double)zz##i.x,a); a = fma((double)zz##i.y,(double)zz##i.y,a); \
                a = fma((double)zz##i.z,(double)zz##i.z,a); a = fma((double)zz##i.w,(double)zz##i.w,a);
#define DOT4(i) e4 = ep[i]; m = fmaf(zz##i.x, e4.x, m); m = fmaf(zz##i.y, e4.y, m); \
                m = fmaf(zz##i.z, e4.z, m); m = fmaf(zz##i.w, e4.w, m);

__global__ __launch_bounds__(256, 2)
void vq_rescue_scan(const float* __restrict__ z, const float* __restrict__ emb,
                    const float* __restrict__ e2f,
                    const unsigned* __restrict__ nflag,
                    const unsigned* __restrict__ rowlist,
                    unsigned long long* __restrict__ keyws) {
    __shared__ float zs[64 * 68];        // 64 rows, stride 68 floats (bank-spread)
    const int t = threadIdx.x, w = t >> 6, lane = t & 63;
    const int g = blockIdx.x >> 2, cg = blockIdx.x & 3;
    unsigned nfr = *nflag;
    const int nf = (int)(nfr < CAPF ? nfr : CAPF);
    if (g * 64 >= nf) return;

    // stage z rows: 4 threads per row, 16 k each (scattered 4B, L2/L3-hot)
    {
        const int r = t >> 2, kb = (t & 3) * 16;
        const int slot = g * 64 + r;
        if (slot < nf) {
            const int row = (int)rowlist[slot];
            const int bb = row >> 10, s = row & 1023;
            const float* zp = z + (size_t)bb * 65536 + s;
            #pragma unroll
            for (int k = 0; k < 16; ++k)
                zs[r * 68 + kb + k] = zp[(size_t)(kb + k) * 1024];
        }
    }
    __syncthreads();

    const int myslot = g * 64 + lane;
    const bool act = myslot < nf;

    // lane's row -> 16 named float4 registers (cannot spill to scratch)
    const float4* zrp = (const float4*)(zs + lane * 68);
    ZLD(0) ZLD(1) ZLD(2) ZLD(3) ZLD(4) ZLD(5) ZLD(6) ZLD(7)
    ZLD(8) ZLD(9) ZLD(10) ZLD(11) ZLD(12) ZLD(13) ZLD(14) ZLD(15)

    // zn = fl32(fp64 ||z||^2), sequential k (R2-proven)
    double a = 0.0;
    ZN4(0) ZN4(1) ZN4(2) ZN4(3) ZN4(4) ZN4(5) ZN4(6) ZN4(7)
    ZN4(8) ZN4(9) ZN4(10) ZN4(11) ZN4(12) ZN4(13) ZN4(14) ZN4(15)
    const float zn = (float)a;

    const int q = cg * 4 + w;            // this wave's 64-code chunk
    float bv = 3.4e38f; int bi = 0x7fffffff;
    #pragma unroll 4
    for (int j = 0; j < 64; ++j) {
        const int c = q * 64 + j;        // ascending within chunk
        const float4* ep = (const float4*)(emb + (size_t)c * 64);  // wave-uniform
        float m = 0.f; float4 e4;
        DOT4(0) DOT4(1) DOT4(2) DOT4(3) DOT4(4) DOT4(5) DOT4(6) DOT4(7)
        DOT4(8) DOT4(9) DOT4(10) DOT4(11) DOT4(12) DOT4(13) DOT4(14) DOT4(15)
        float tt = zn + e2f[c];
        float d = tt - 2.0f * m;
        if (d < bv || (d == bv && c < bi)) { bv = d; bi = c; }
    }
    if (act) atomicMin(&keyws[myslot], packkey(bv, bi));
}

// ---------------- rescue fin: wave per flagged row, outputs (validated round-1 tail) ----------------
__global__ __launch_bounds__(256, 1)
void vq_rescue_fin(const float* __restrict__ z, const float* __restrict__ emb,
                   float* __restrict__ out, double* __restrict__ loss_sum,
                   unsigned* __restrict__ hist,
                   const unsigned* __restrict__ nflag,
                   const unsigned* __restrict__ rowlist,
                   const unsigned long long* __restrict__ keyws) {
    const int w = threadIdx.x >> 6, lane = threadIdx.x & 63;
    unsigned nfr = *nflag;
    const int nf = (int)(nfr < CAPF ? nfr : CAPF);
    const int slot = blockIdx.x * 4 + w;
    if (slot >= nf) return;
    const int row = (int)rowlist[slot];
    const int b = row >> 10, s = row & 1023;
    const int bi = (int)(unsigned)(keyws[slot] & 0xffffffffu);

    const float e = emb[bi * 64 + lane];
    const size_t off = (size_t)b * 65536 + (size_t)lane * 1024 + s;
    const float zv = z[off];                        // L2/L3-hot
    out[off] = zv + (e - zv);
    double df = (double)e - (double)zv;
    double lsum = df * df;
    #pragma unroll
    for (int o = 32; o > 0; o >>= 1) lsum += __shfl_down(lsum, o, 64);
    if (lane == 0) {
        out[NELEM + row] = (float)bi;
        atomicAdd(&hist[bi], 1u);
        atomicAdd(loss_sum, lsum);
    }
}

// ---------------- finalize ----------------
__global__ void vq_finalize_kernel(const unsigned* __restrict__ hist,
                                   const double* __restrict__ loss_sum,
                                   float* __restrict__ out) {
    __shared__ double red[256];
    int t = threadIdx.x;
    double ssum = 0.0;
    for (int i = t; i < VOCAB; i += 256) {
        double p = (double)hist[i] / (double)NROWS;
        ssum += p * log(p + 1e-10);
    }
    red[t] = ssum;
    __syncthreads();
    for (int off = 128; off > 0; off >>= 1) {
        if (t < off) red[t] += red[t + off];
        __syncthreads();
    }
    if (t == 0) {
        double qv = loss_sum[0] / (double)NELEM;
        out[NELEM + NROWS + 0] = (float)qv;
        out[NELEM + NROWS + 1] = (float)(qv * 0.25);
        out[NELEM + NROWS + 2] = (float)exp(-red[0]);
    }
}

extern "C" void kernel_launch(void* const* d_in, const int* in_sizes, int n_in,
                              void* d_out, int out_size, void* d_ws, size_t ws_size,
                              hipStream_t stream) {
    const float* z   = (const float*)d_in[0];   // (64,64,32,32) fp32
    const float* emb = (const float*)d_in[1];   // (1024,64) fp32
    float* out = (float*)d_out;

    float*              e2f     = (float*)d_ws;
    double*             loss    = (double*)((char*)d_ws + 4096);
    unsigned*           nfl     = (unsigned*)((char*)d_ws + 4104);
    unsigned*           hist    = (unsigned*)((char*)d_ws + 4112);
    unsigned*           rowlist = (unsigned*)((char*)d_ws + 8208);
    uint4*              FB      = (uint4*)((char*)d_ws + 40976);
    unsigned long long* keyws   = (unsigned long long*)((char*)d_ws + 172048);

    // zero loss + nflag + pad + hist; keys init to +inf (all-ones)
    hipMemsetAsync((char*)d_ws + 4096, 0, 4112, stream);
    hipMemsetAsync((char*)d_ws + 172048, 0xFF, CAPF * 8, stream);

    vq_prep<<<dim3(8), dim3(256), 0, stream>>>(emb, e2f, FB);
    vq_filter<<<dim3(1024), dim3(256), 0, stream>>>(z, emb, e2f, FB, out, loss,
                                                    hist, nfl, rowlist);
    vq_rescue_scan<<<dim3((CAPF / 64) * 4), dim3(256), 0, stream>>>(z, emb, e2f,
                                                                    nfl, rowlist,
                                                                    keyws);
    vq_rescue_fin<<<dim3(CAPF / 4), dim3(256), 0, stream>>>(z, emb, out, loss,
                                                            hist, nfl, rowlist,
                                                            keyws);
    vq_finalize_kernel<<<dim3(1), dim3(256), 0, stream>>>(hist, loss, out);
}

// Round 3
// 251.756 us; speedup vs baseline: 1.2723x; 1.1893x over previous
//
#include <hip/hip_runtime.h>
#include <math.h>

#define VOCAB 1024
#define ED 64
#define NROWS 65536            // 64*32*32 flattened rows
#define NELEM 4194304          // 64*64*32*32
#define MARGIN 2.0e-4f         // validated R3/R4 (passed, absmax 0)
#define CAPF 8192              // flagged-row slots (expect ~2500-4200)

typedef __attribute__((ext_vector_type(8))) short short8;
typedef __attribute__((ext_vector_type(4))) float f32x4;

__device__ __forceinline__ unsigned f2bf(float f) {
    unsigned u = __float_as_uint(f);
    u += 0x7fff + ((u >> 16) & 1);   // RNE to bf16
    return u >> 16;
}

// pack (distance, code) into a sortable u64 key: min(key) == lex-min (d, c)
__device__ __forceinline__ unsigned long long packkey(float d, int c) {
    unsigned f = __float_as_uint(d);
    unsigned sd = (f & 0x80000000u) ? ~f : (f | 0x80000000u);
    return ((unsigned long long)sd << 32) | (unsigned)c;
}

// ws layout:
//   [0,      4096)   float e2f[1024]     fl32(fp64 ||e||^2)  (R2-proven)
//   [4096,   4100)   unsigned nflag
//   [4100,   4112)   pad
//   [4112,   8208)   unsigned hist[1024]
//   [8208,   40976)  unsigned rowlist[CAPF]
//   [40976,  172048) uint4 FB[8192]      bf16 MFMA-B fragments (128 KB)
//   [172048, 180240) double lossp[1024]  per-filter-block loss partials
//   [180240, 181264) double lossp2[128]  per-rescue-block loss partials
//
// FB fragment layout (identical bits to round-0 stage_chunk):
//   entry i: n=i&15, q=(i>>4)&3, kh=(i>>6)&1, T=i>>7
//   holds bf16x8 of emb[T*16+n][kh*32+q*8 .. +8)
//   filter reads bf[kh] = ((short8*)FB)[T*128 + kh*64 + lane], lane=q*16+n_lo

// ---------------- prep: e2f + bf16 fragment table + workspace zeroing ----------------
__global__ void vq_prep(const float* __restrict__ emb, float* __restrict__ e2f,
                        uint4* __restrict__ FB, unsigned* __restrict__ zw1,
                        unsigned* __restrict__ zw2) {
    const int tid = blockIdx.x * 256 + threadIdx.x;   // 0..2047
    // zero nflag+pad+hist (1028 words) and lossp+lossp2 (2304 words)
    for (int i = tid; i < 1028; i += 2048) zw1[i] = 0u;
    for (int i = tid; i < 2304; i += 2048) zw2[i] = 0u;

    if (tid < VOCAB) {
        const float4* src = (const float4*)(emb + tid * ED);
        double s = 0.0;
        #pragma unroll
        for (int g = 0; g < 16; ++g) {
            float4 f = src[g];
            s = fma((double)f.x, (double)f.x, s);
            s = fma((double)f.y, (double)f.y, s);
            s = fma((double)f.z, (double)f.z, s);
            s = fma((double)f.w, (double)f.w, s);
        }
        e2f[tid] = (float)s;
    }
    #pragma unroll
    for (int e = 0; e < 4; ++e) {
        const int i = e * 2048 + tid;                 // 0..8191
        const int n = i & 15, q = (i >> 4) & 3, kh = (i >> 6) & 1, T = i >> 7;
        const int code = T * 16 + n;
        const int k0 = kh * 32 + q * 8;
        const float4* sp = (const float4*)(emb + code * 64 + k0);
        float4 f0 = sp[0], f1 = sp[1];
        uint4 pk;
        pk.x = f2bf(f0.x) | (f2bf(f0.y) << 16);
        pk.y = f2bf(f0.z) | (f2bf(f0.w) << 16);
        pk.z = f2bf(f1.x) | (f2bf(f1.y) << 16);
        pk.w = f2bf(f1.z) | (f2bf(f1.w) << 16);
        FB[i] = pk;
    }
}

// ---------------- filter: 1024 blocks x 64 rows, FB direct from global, no atomic storms ----------------
__global__ __launch_bounds__(256, 4)
void vq_filter(const float* __restrict__ z, const float* __restrict__ emb,
               const float* __restrict__ e2f, const uint4* __restrict__ FB,
               float* __restrict__ out, double* __restrict__ lossp,
               unsigned* __restrict__ hist, unsigned* __restrict__ nflag,
               unsigned* __restrict__ rowlist) {
    __shared__ float e2s[1024];
    __shared__ float rowb1[64], rowb2[64];
    __shared__ int   rowi1[64], rowfl[64];
    __shared__ double wls[4];

    const int t = threadIdx.x;
    const int w = t >> 6, lane = t & 63;
    const int q = lane >> 4, n_lo = lane & 15;
    const int bk = blockIdx.x;           // 1024 blocks, 64 rows each
    const int n0 = bk * 64;
    const int b  = n0 >> 10;
    const int sb = n0 & 1023;

    #pragma unroll
    for (int i = 0; i < 4; ++i) e2s[i * 256 + t] = e2f[i * 256 + t];

    // A fragments: bf16(-2 z) for this wave's 16 rows (bit-identical values per row)
    short8 af[2];
    {
        const int s = sb + w * 16 + n_lo;
        const float* zp = z + (size_t)b * 65536 + s;
        #pragma unroll
        for (int kh = 0; kh < 2; ++kh) {
            short8 fr;
            #pragma unroll
            for (int j = 0; j < 8; ++j) {
                int d = kh * 32 + q * 8 + j;
                fr[j] = (short)f2bf(-2.0f * zp[d * 1024]);
            }
            af[kh] = fr;
        }
    }

    float b1[4], b2[4]; int i1[4];
    #pragma unroll
    for (int sl = 0; sl < 4; ++sl) { b1[sl] = 3.4e38f; b2[sl] = 3.4e38f; i1[sl] = 0; }

    __syncthreads();                     // e2s ready

    // ---- MFMA scan: 64 tiles, B-fragments straight from global (L2-hot, 128 KB) ----
    const short8* FBs = (const short8*)FB;
    #pragma unroll 4
    for (int T = 0; T < 64; ++T) {
        short8 bf0 = FBs[T * 128 + lane];          // kh=0
        short8 bf1 = FBs[T * 128 + 64 + lane];     // kh=1
        const int cb = T * 16 + n_lo;
        const float e2 = e2s[cb];
        f32x4 a; a[0] = e2; a[1] = e2; a[2] = e2; a[3] = e2;
        a = __builtin_amdgcn_mfma_f32_16x16x32_bf16(af[0], bf0, a, 0, 0, 0);
        a = __builtin_amdgcn_mfma_f32_16x16x32_bf16(af[1], bf1, a, 0, 0, 0);
        #pragma unroll
        for (int reg = 0; reg < 4; ++reg) {
            float s0 = a[reg];
            b2[reg] = __builtin_amdgcn_fmed3f(s0, b1[reg], b2[reg]);
            bool lt = s0 < b1[reg];
            i1[reg] = lt ? cb : i1[reg];
            b1[reg] = lt ? s0 : b1[reg];
        }
    }

    // merge across the 16 code-lanes of each quad (identical to validated logic)
    #pragma unroll
    for (int m = 1; m < 16; m <<= 1) {
        #pragma unroll
        for (int sl = 0; sl < 4; ++sl) {
            float ob1 = __shfl_xor(b1[sl], m, 64);
            int   oi1 = __shfl_xor(i1[sl], m, 64);
            float ob2 = __shfl_xor(b2[sl], m, 64);
            float lose = fmaxf(b1[sl], ob1);
            b2[sl] = fminf(fminf(b2[sl], ob2), lose);
            bool take = (ob1 < b1[sl]) || (ob1 == b1[sl] && oi1 < i1[sl]);
            b1[sl] = take ? ob1 : b1[sl];
            i1[sl] = take ? oi1 : i1[sl];
        }
    }
    if (n_lo == 0) {
        #pragma unroll
        for (int reg = 0; reg < 4; ++reg) {
            int row = w * 16 + q * 4 + reg;
            rowb1[row] = b1[reg];
            rowb2[row] = b2[reg];
            rowi1[row] = i1[reg];
        }
    }
    __syncthreads();

    // ---- flag rows (wave 0): ballot-compaction, ONE reserve atomic per block ----
    if (t < 64) {
        const int nrow = n0 + t;
        const int code = rowi1[t];
        const bool want = rowb2[t] < rowb1[t] + MARGIN;
        unsigned long long mask = __ballot(want);
        const int cnt = __popcll(mask);
        unsigned base = 0;
        if (t == 0 && cnt > 0) base = atomicAdd(nflag, (unsigned)cnt);
        base = (unsigned)__shfl((int)base, 0, 64);
        int f = 0;
        if (want) {
            const int rank = __popcll(mask & ((1ULL << t) - 1ULL));
            const unsigned slot = base + (unsigned)rank;
            if (slot < CAPF) { rowlist[slot] = (unsigned)nrow; f = 1; }
            // overflow (slot>=CAPF): treated unflagged, same as validated kernel
        }
        rowfl[t] = f;
        out[NELEM + nrow] = (float)code;   // rescue overwrites if flagged
        if (!f) atomicAdd(&hist[code], 1u);
    }
    __syncthreads();

    // ---- epilogue: COALESCED z_q_st + loss. Thread (w,lane): row=lane, dims [w*16,w*16+16) ----
    {
        const int r = lane;
        const int code2 = rowi1[r];
        const bool fl2 = rowfl[r] != 0;
        const int scol = sb + r;
        double lsum = 0.0;
        #pragma unroll
        for (int i = 0; i < 4; ++i) {
            const int d4 = w * 4 + i;
            float4 e4 = *(const float4*)(emb + code2 * 64 + d4 * 4);  // gather, L1/L2-hot
            float es[4] = {e4.x, e4.y, e4.z, e4.w};
            #pragma unroll
            for (int j = 0; j < 4; ++j) {
                int d = d4 * 4 + j;
                size_t off = (size_t)b * 65536 + (size_t)d * 1024 + scol;
                float zv = z[off];                 // coalesced 256B
                out[off] = zv + (es[j] - zv);      // coalesced 256B
                double df = (double)es[j] - (double)zv;
                lsum = fma(df, df, lsum);
            }
        }
        if (fl2) lsum = 0.0;                       // rescue adds flagged rows' loss
        #pragma unroll
        for (int off = 32; off > 0; off >>= 1)
            lsum += __shfl_down(lsum, off, 64);
        if (lane == 0) wls[w] = lsum;
    }
    __syncthreads();
    if (t == 0) lossp[bk] = wls[0] + wls[1] + wls[2] + wls[3];   // NO atomic
}

// ---------------- rescue: ONE kernel. Block = 64 rows (lane<->row), 8 waves x 128 codes ----------------
#define ZLD(i)  float4 zz##i = zrp[i];
#define ZN4(i)  a = fma((double)zz##i.x,(double)zz##i.x,a); a = fma((double)zz##i.y,(double)zz##i.y,a); \
                a = fma((double)zz##i.z,(double)zz##i.z,a); a = fma((double)zz##i.w,(double)zz##i.w,a);
#define DOT4(i) e4 = ep[i]; m = fmaf(zz##i.x, e4.x, m); m = fmaf(zz##i.y, e4.y, m); \
                m = fmaf(zz##i.z, e4.z, m); m = fmaf(zz##i.w, e4.w, m);

__global__ __launch_bounds__(512, 2)
void vq_rescue(const float* __restrict__ z, const float* __restrict__ emb,
               const float* __restrict__ e2f, float* __restrict__ out,
               double* __restrict__ lossp2, unsigned* __restrict__ hist,
               const unsigned* __restrict__ nflag,
               const unsigned* __restrict__ rowlist) {
    __shared__ float zs[64 * 68];            // 64 rows, stride 68 floats (272B, 16B-aligned)
    __shared__ unsigned long long wkey[8][64];
    __shared__ int rbi[64];
    __shared__ double lred[8];

    const int t = threadIdx.x, w = t >> 6, lane = t & 63;
    const int g = blockIdx.x;                // 128 blocks, 64 slots each
    unsigned nfr = *nflag;
    const int nf = (int)(nfr < CAPF ? nfr : CAPF);
    if (g * 64 >= nf) return;
    const int nloc = (nf - g * 64 < 64) ? (nf - g * 64) : 64;

    // stage z rows: 8 threads per row, 8 k each (scattered 4B, L2/L3-hot)
    {
        const int r = t >> 3, kb = (t & 7) * 8;
        if (r < nloc) {
            const int row = (int)rowlist[g * 64 + r];
            const int bb = row >> 10, s = row & 1023;
            const float* zp = z + (size_t)bb * 65536 + s;
            #pragma unroll
            for (int k = 0; k < 8; ++k)
                zs[r * 68 + kb + k] = zp[(size_t)(kb + k) * 1024];
        }
    }
    __syncthreads();

    const bool act = lane < nloc;

    // lane's row -> 16 named float4 registers (cannot spill to scratch)
    const float4* zrp = (const float4*)(zs + lane * 68);
    ZLD(0) ZLD(1) ZLD(2) ZLD(3) ZLD(4) ZLD(5) ZLD(6) ZLD(7)
    ZLD(8) ZLD(9) ZLD(10) ZLD(11) ZLD(12) ZLD(13) ZLD(14) ZLD(15)

    // zn = fl32(fp64 ||z||^2), sequential k (R2-proven)
    double a = 0.0;
    ZN4(0) ZN4(1) ZN4(2) ZN4(3) ZN4(4) ZN4(5) ZN4(6) ZN4(7)
    ZN4(8) ZN4(9) ZN4(10) ZN4(11) ZN4(12) ZN4(13) ZN4(14) ZN4(15)
    const float zn = (float)a;

    // wave w scans codes [w*128, (w+1)*128), ascending; exact R2 fp32 chain per code
    float bv = 3.4e38f; int bi = 0x7fffffff;
    #pragma unroll 4
    for (int j = 0; j < 128; ++j) {
        const int c = w * 128 + j;
        const float4* ep = (const float4*)(emb + (size_t)c * 64);  // wave-uniform
        float m = 0.f; float4 e4;
        DOT4(0) DOT4(1) DOT4(2) DOT4(3) DOT4(4) DOT4(5) DOT4(6) DOT4(7)
        DOT4(8) DOT4(9) DOT4(10) DOT4(11) DOT4(12) DOT4(13) DOT4(14) DOT4(15)
        float tt = zn + e2f[c];
        float d = tt - 2.0f * m;
        if (d < bv || (d == bv && c < bi)) { bv = d; bi = c; }
    }
    wkey[w][lane] = packkey(bv, bi);
    __syncthreads();

    // merge 8 wave-candidates per row (lex-min key), write index + hist (wave 0)
    if (w == 0) {
        unsigned long long k0 = wkey[0][lane];
        #pragma unroll
        for (int i = 1; i < 8; ++i) {
            unsigned long long ki = wkey[i][lane];
            if (ki < k0) k0 = ki;
        }
        const int code = (int)(unsigned)(k0 & 0xffffffffu);
        rbi[lane] = code;
        if (act) {
            const int row = (int)rowlist[g * 64 + lane];
            out[NELEM + row] = (float)code;
            atomicAdd(&hist[code], 1u);      // distributed addresses
        }
    }
    __syncthreads();

    // outputs + loss: 8 threads per row, 8 dims each; z from LDS (no global re-read)
    double lsum = 0.0;
    {
        const int r = t >> 3, d0 = (t & 7) * 8;
        if (r < nloc) {
            const int row = (int)rowlist[g * 64 + r];
            const int bb = row >> 10, s = row & 1023;
            const int code = rbi[r];
            float4 ea = *(const float4*)(emb + code * 64 + d0);
            float4 eb = *(const float4*)(emb + code * 64 + d0 + 4);
            float es[8] = {ea.x, ea.y, ea.z, ea.w, eb.x, eb.y, eb.z, eb.w};
            #pragma unroll
            for (int j = 0; j < 8; ++j) {
                const int d = d0 + j;
                const float zv = zs[r * 68 + d];
                out[(size_t)bb * 65536 + (size_t)d * 1024 + s] = zv + (es[j] - zv);
                double df = (double)es[j] - (double)zv;
                lsum = fma(df, df, lsum);
            }
        }
    }
    #pragma unroll
    for (int o = 32; o > 0; o >>= 1) lsum += __shfl_down(lsum, o, 64);
    if (lane == 0) lred[w] = lsum;
    __syncthreads();
    if (t == 0) {
        double s = 0.0;
        #pragma unroll
        for (int i = 0; i < 8; ++i) s += lred[i];
        lossp2[g] = s;                        // NO atomic
    }
}

// ---------------- finalize: sum loss partials + entropy ----------------
__global__ void vq_finalize_kernel(const unsigned* __restrict__ hist,
                                   const double* __restrict__ lossp,
                                   const double* __restrict__ lossp2,
                                   float* __restrict__ out) {
    __shared__ double red[256], red2[256];
    int t = threadIdx.x;
    double ssum = 0.0, lsum = 0.0;
    for (int i = t; i < VOCAB; i += 256) {
        double p = (double)hist[i] / (double)NROWS;
        ssum += p * log(p + 1e-10);
    }
    for (int i = t; i < 1024; i += 256) lsum += lossp[i];
    if (t < 128) lsum += lossp2[t];
    red[t] = ssum; red2[t] = lsum;
    __syncthreads();
    for (int off = 128; off > 0; off >>= 1) {
        if (t < off) { red[t] += red[t + off]; red2[t] += red2[t + off]; }
        __syncthreads();
    }
    if (t == 0) {
        double qv = red2[0] / (double)NELEM;
        out[NELEM + NROWS + 0] = (float)qv;
        out[NELEM + NROWS + 1] = (float)(qv * 0.25);
        out[NELEM + NROWS + 2] = (float)exp(-red[0]);
    }
}

extern "C" void kernel_launch(void* const* d_in, const int* in_sizes, int n_in,
                              void* d_out, int out_size, void* d_ws, size_t ws_size,
                              hipStream_t stream) {
    const float* z   = (const float*)d_in[0];   // (64,64,32,32) fp32
    const float* emb = (const float*)d_in[1];   // (1024,64) fp32
    float* out = (float*)d_out;

    float*    e2f     = (float*)d_ws;
    unsigned* nfl     = (unsigned*)((char*)d_ws + 4096);
    unsigned* hist    = (unsigned*)((char*)d_ws + 4112);
    unsigned* rowlist = (unsigned*)((char*)d_ws + 8208);
    uint4*    FB      = (uint4*)((char*)d_ws + 40976);
    double*   lossp   = (double*)((char*)d_ws + 172048);
    double*   lossp2  = (double*)((char*)d_ws + 180240);
    unsigned* zw1     = (unsigned*)((char*)d_ws + 4096);    // nflag+pad+hist (1028 words)
    unsigned* zw2     = (unsigned*)((char*)d_ws + 172048);  // lossp+lossp2 (2304 words)

    vq_prep<<<dim3(8), dim3(256), 0, stream>>>(emb, e2f, FB, zw1, zw2);
    vq_filter<<<dim3(1024), dim3(256), 0, stream>>>(z, emb, e2f, FB, out, lossp,
                                                    hist, nfl, rowlist);
    vq_rescue<<<dim3(128), dim3(512), 0, stream>>>(z, emb, e2f, out, lossp2,
                                                   hist, nfl, rowlist);
    vq_finalize_kernel<<<dim3(1), dim3(256), 0, stream>>>(hist, lossp, lossp2, out);
}